// Round 17
// baseline (454.954 us; speedup 1.0000x reference)
//
#include <hip/hip_runtime.h>
#include <hip/hip_fp16.h>

#define N_NODES 100000
#define N_EDGES 3200000
#define N_GRAPHS 2048
#define MOL 78
#define HID 32
#define OUTD 128
#define BN_EPS 1e-5f

// Partition: buckets of 256 nodes (dst >> 8)
#define NBUCK ((N_NODES + 255) / 256)  // 391
#define BCAP2 9216                     // mean 8184, sigma ~90 -> +11 sigma
#define EPB 4096                       // edges per part1 block
#define P1_BLOCKS ((N_EDGES + EPB - 1) / EPB)  // 782

#define NPH 4                             // nodes per half-wave
#define CPL_BLOCKS (N_NODES / (8 * NPH))  // 3125 (exact)

#define NCOPY 64  // BN-sum accumulator copies (kills same-address atomic serialization)

// fp16 payload helpers (RNE pack, exact unpack)
__device__ inline unsigned int pkh2(float a, float b) {
    __half2 h = __halves2half2(__float2half_rn(a), __float2half_rn(b));
    return *(unsigned int*)&h;
}
__device__ inline float hlo(unsigned int v) {
    __half2 h = *(__half2*)&v;
    return __low2float(h);
}
__device__ inline float hhi(unsigned int v) {
    __half2 h = *(__half2*)&v;
    return __high2float(h);
}

// ---------------- CSR build: LDS-staged two-pass bucket sort ----------------

__global__ __launch_bounds__(256) void part1_kernel(const int* __restrict__ src,
                                                    const int* __restrict__ dst,
                                                    int* __restrict__ gcur,
                                                    int* __restrict__ staging) {
    __shared__ int hist[NBUCK];
    __shared__ int lofs[NBUCK];
    __shared__ int lcur[NBUCK];
    __shared__ int gb[NBUCK];
    __shared__ int pk[EPB];
    __shared__ unsigned short bkt[EPB];
    __shared__ int sc[256];
    const int t = threadIdx.x;
    const int base = blockIdx.x * EPB;
    const int nedge = min(EPB, N_EDGES - base);

    for (int i = t; i < NBUCK; i += 256) hist[i] = 0;
    __syncthreads();
    for (int i = t; i < nedge; i += 256) atomicAdd(&hist[dst[base + i] >> 8], 1);
    __syncthreads();

    int a0 = (2 * t < NBUCK) ? hist[2 * t] : 0;
    int a1 = (2 * t + 1 < NBUCK) ? hist[2 * t + 1] : 0;
    int tot = a0 + a1;
    sc[t] = tot;
    __syncthreads();
    for (int off = 1; off < 256; off <<= 1) {
        int add = (t >= off) ? sc[t - off] : 0;
        __syncthreads();
        sc[t] += add;
        __syncthreads();
    }
    int excl = sc[t] - tot;
    if (2 * t < NBUCK) { lofs[2 * t] = excl; lcur[2 * t] = excl; }
    if (2 * t + 1 < NBUCK) { lofs[2 * t + 1] = excl + a0; lcur[2 * t + 1] = excl + a0; }
    __syncthreads();

    for (int i = t; i < nedge; i += 256) {
        int d = dst[base + i];
        int s = src[base + i];
        int b = d >> 8;
        int p = atomicAdd(&lcur[b], 1);
        pk[p] = (s << 8) | (d & 255);
        bkt[p] = (unsigned short)b;
    }
    __syncthreads();

    for (int b = t; b < NBUCK; b += 256) {
        int c = lcur[b] - lofs[b];
        gb[b] = c ? atomicAdd(&gcur[b], c) : 0;
    }
    __syncthreads();

    for (int i = t; i < nedge; i += 256) {
        int b = bkt[i];
        staging[(size_t)b * BCAP2 + gb[b] + (i - lofs[b])] = pk[i];
    }
}

__global__ void csrbase_kernel(const int* __restrict__ gcur, int* __restrict__ bbase,
                               int* __restrict__ row_start) {
    int t = threadIdx.x;
    int a0 = (2 * t < NBUCK) ? gcur[2 * t] : 0;
    int a1 = (2 * t + 1 < NBUCK) ? gcur[2 * t + 1] : 0;
    int tot = a0 + a1;
    __shared__ int sc[256];
    sc[t] = tot;
    __syncthreads();
    for (int off = 1; off < 256; off <<= 1) {
        int add = (t >= off) ? sc[t - off] : 0;
        __syncthreads();
        sc[t] += add;
        __syncthreads();
    }
    int excl = sc[t] - tot;
    if (2 * t < NBUCK) bbase[2 * t] = excl;
    if (2 * t + 1 < NBUCK) bbase[2 * t + 1] = excl + a0;
    if (t == 0) row_start[N_NODES] = N_EDGES;
}

__global__ __launch_bounds__(256) void part2_kernel(const int* __restrict__ gcur,
                                                    const int* __restrict__ bbase,
                                                    const int* __restrict__ staging,
                                                    int* __restrict__ row_start,
                                                    int* __restrict__ csr,
                                                    float* __restrict__ degf) {
    int b = blockIdx.x, t = threadIdx.x;
    __shared__ int ldeg[256];
    __shared__ int lex[256];
    __shared__ int sc[256];
    ldeg[t] = 0;
    __syncthreads();
    int cnt = gcur[b];
    int base = bbase[b];
    const int* sp = staging + (size_t)b * BCAP2;
    for (int i = t; i < cnt; i += 256) atomicAdd(&ldeg[sp[i] & 255], 1);
    __syncthreads();
    int v = ldeg[t];
    sc[t] = v;
    __syncthreads();
    for (int off = 1; off < 256; off <<= 1) {
        int add = (t >= off) ? sc[t - off] : 0;
        __syncthreads();
        sc[t] += add;
        __syncthreads();
    }
    int excl = sc[t] - v;
    int node = b * 256 + t;
    if (node < N_NODES) {
        row_start[node] = base + excl;
        degf[node] = 1.0f + (float)v;
    }
    lex[t] = base + excl;
    __syncthreads();
    for (int i = t; i < cnt; i += 256) {
        int pk = sp[i];
        int p = atomicAdd(&lex[pk & 255], 1);
        csr[p] = pk >> 8;
    }
}

// ---------------- Graph node counts (batch is sorted) ----------------

__global__ void gcnt_kernel(const int* __restrict__ batch, int* __restrict__ cnt) {
    int g = blockIdx.x * blockDim.x + threadIdx.x;
    if (g >= N_GRAPHS) return;
    auto lb = [&](int key) {
        int lo = 0, hi = N_NODES;
        while (lo < hi) {
            int mid = (lo + hi) >> 1;
            if (batch[mid] < key) lo = mid + 1; else hi = mid;
        }
        return lo;
    };
    cnt[g] = lb(g + 1) - lb(g);
}

// ---------------- Layer-0 projection (78 -> 32), fp16 output ----------------

__global__ __launch_bounds__(256) void proj78_kernel(const float* __restrict__ in,
                                                     const float* __restrict__ W1,
                                                     unsigned int* __restrict__ y) {
    __shared__ float w1s[MOL * HID];
    for (int i = threadIdx.x; i < MOL * HID; i += 256) w1s[i] = W1[i];
    __syncthreads();
    const int node = blockIdx.x * 256 + threadIdx.x;
    if (node >= N_NODES) return;
    const float* row = in + (size_t)node * MOL;
    float acc[HID];
#pragma unroll
    for (int j = 0; j < HID; j++) acc[j] = 0.f;
    const float4* w1v = (const float4*)w1s;
    for (int k = 0; k < MOL; k++) {
        float xv = row[k];
#pragma unroll
        for (int q = 0; q < 8; q++) {
            float4 wv = w1v[k * 8 + q];
            acc[4 * q + 0] = fmaf(xv, wv.x, acc[4 * q + 0]);
            acc[4 * q + 1] = fmaf(xv, wv.y, acc[4 * q + 1]);
            acc[4 * q + 2] = fmaf(xv, wv.z, acc[4 * q + 2]);
            acc[4 * q + 3] = fmaf(xv, wv.w, acc[4 * q + 3]);
        }
    }
    uint4* o = (uint4*)(y + (size_t)node * 16);
#pragma unroll
    for (int g = 0; g < 4; g++) {
        uint4 u;
        u.x = pkh2(acc[8 * g + 0], acc[8 * g + 1]);
        u.y = pkh2(acc[8 * g + 2], acc[8 * g + 3]);
        u.z = pkh2(acc[8 * g + 4], acc[8 * g + 5]);
        u.w = pkh2(acc[8 * g + 6], acc[8 * g + 7]);
        o[g] = u;
    }
}

// ---------------- Fused gather + MLP + BN stats (one kernel per layer) ----------------
// MODE 0: layer 0 — v = ReLU(agg + B1) at LDS write; W2 matvec.
// MODE 1: mid layers — u = sc*agg + degf*sh at LDS write; W1 + ReLU; W2.
// MODE 2: last layer — like MODE 1 but pools raw h via atomics.
// Weight columns are loaded then PINNED into VGPRs via asm identity — without the
// pin, LLVM rematerializes the loads inside the fmaf loops (observed VGPR=40,
// phase 2 ~40us latency-bound on per-fmaf global loads).
// y (gather input) and out MUST be different buffers (round-14 race).

template <int MODE>
__global__ __launch_bounds__(256, 4) void gma_kernel(
    const unsigned int* __restrict__ y, const int* __restrict__ rs, const int* __restrict__ csr,
    const float* __restrict__ degf, const float* __restrict__ scsh_prev,
    const float* __restrict__ B1, const float* __restrict__ W1, const float* __restrict__ W2,
    const float* __restrict__ B2, __half* __restrict__ out, float* __restrict__ sums,
    const int* __restrict__ batch, float* __restrict__ pooledraw) {
    __shared__ float ldsu[8][NPH][HID];
    __shared__ float ldsv[8][NPH][HID];
    __shared__ float ssum[64];
    const int t = threadIdx.x;
    const int hw = t >> 5;
    const int hl = t & 31;
    const int s = hl >> 2;  // slot 0..7
    const int q = hl & 3;   // quad: channels 8q..8q+7
    const int c = hl;       // channel for matvec phase
    if (t < 64) ssum[t] = 0.f;

    // per-quad transform params (used by slot-0 lanes at LDS write)
    float4 p0a, p0b, p1a, p1b;
    if (MODE == 0) {
        p0a = ((const float4*)B1)[2 * q];
        p0b = ((const float4*)B1)[2 * q + 1];
    } else {
        p0a = ((const float4*)scsh_prev)[2 * q];          // sc[8q..]
        p0b = ((const float4*)scsh_prev)[2 * q + 1];
        p1a = ((const float4*)(scsh_prev + HID))[2 * q];  // sh[8q..]
        p1b = ((const float4*)(scsh_prev + HID))[2 * q + 1];
    }

    const int n0 = (blockIdx.x * 8 + hw) * NPH;
    const uint4* rows = (const uint4*)y;

    // ---- Phase 1: gather NPH nodes ----
    for (int u = 0; u < NPH; u++) {
        const int n = n0 + u;
        float acc[8];
#pragma unroll
        for (int i = 0; i < 8; i++) acc[i] = 0.f;
        if (s == 0) {
            uint4 w = rows[(size_t)n * 4 + q];
            acc[0] = hlo(w.x); acc[1] = hhi(w.x);
            acc[2] = hlo(w.y); acc[3] = hhi(w.y);
            acc[4] = hlo(w.z); acc[5] = hhi(w.z);
            acc[6] = hlo(w.w); acc[7] = hhi(w.w);
        }
        int e0 = rs[n], e1 = rs[n + 1];
        int k = e0 + s;
        for (; k + 8 < e1; k += 16) {
            uint4 a = rows[(size_t)csr[k] * 4 + q];
            uint4 b = rows[(size_t)csr[k + 8] * 4 + q];
            acc[0] += hlo(a.x) + hlo(b.x);
            acc[1] += hhi(a.x) + hhi(b.x);
            acc[2] += hlo(a.y) + hlo(b.y);
            acc[3] += hhi(a.y) + hhi(b.y);
            acc[4] += hlo(a.z) + hlo(b.z);
            acc[5] += hhi(a.z) + hhi(b.z);
            acc[6] += hlo(a.w) + hlo(b.w);
            acc[7] += hhi(a.w) + hhi(b.w);
        }
        if (k < e1) {
            uint4 a = rows[(size_t)csr[k] * 4 + q];
            acc[0] += hlo(a.x); acc[1] += hhi(a.x);
            acc[2] += hlo(a.y); acc[3] += hhi(a.y);
            acc[4] += hlo(a.z); acc[5] += hhi(a.z);
            acc[6] += hlo(a.w); acc[7] += hhi(a.w);
        }
#pragma unroll
        for (int m = 4; m <= 16; m <<= 1) {
#pragma unroll
            for (int i = 0; i < 8; i++) acc[i] += __shfl_xor(acc[i], m, 32);
        }
        if (s == 0) {
            float o[8];
            if (MODE == 0) {
                o[0] = fmaxf(acc[0] + p0a.x, 0.f); o[1] = fmaxf(acc[1] + p0a.y, 0.f);
                o[2] = fmaxf(acc[2] + p0a.z, 0.f); o[3] = fmaxf(acc[3] + p0a.w, 0.f);
                o[4] = fmaxf(acc[4] + p0b.x, 0.f); o[5] = fmaxf(acc[5] + p0b.y, 0.f);
                o[6] = fmaxf(acc[6] + p0b.z, 0.f); o[7] = fmaxf(acc[7] + p0b.w, 0.f);
            } else {
                float dn = degf[n];
                o[0] = fmaf(acc[0], p0a.x, dn * p1a.x);
                o[1] = fmaf(acc[1], p0a.y, dn * p1a.y);
                o[2] = fmaf(acc[2], p0a.z, dn * p1a.z);
                o[3] = fmaf(acc[3], p0a.w, dn * p1a.w);
                o[4] = fmaf(acc[4], p0b.x, dn * p1b.x);
                o[5] = fmaf(acc[5], p0b.y, dn * p1b.y);
                o[6] = fmaf(acc[6], p0b.z, dn * p1b.z);
                o[7] = fmaf(acc[7], p0b.w, dn * p1b.w);
            }
            float4* d = (float4*)&ldsu[hw][u][q * 8];
            d[0] = make_float4(o[0], o[1], o[2], o[3]);
            d[1] = make_float4(o[4], o[5], o[6], o[7]);
        }
    }

    // ---- Phase 2: matvec(s), weights pinned in VGPRs, ILP=NPH chains ----
    float w2col[32];
#pragma unroll
    for (int k = 0; k < 32; k++) w2col[k] = W2[k * 32 + c];
#pragma unroll
    for (int k = 0; k < 32; k++) asm volatile("" : "+v"(w2col[k]));
    const float b2c = B2[c];
    float sl = 0.f, sq = 0.f;

    if (MODE == 0) {
        float h[NPH];
#pragma unroll
        for (int u = 0; u < NPH; u++) h[u] = b2c;
#pragma unroll
        for (int qq = 0; qq < 8; qq++) {
#pragma unroll
            for (int u = 0; u < NPH; u++) {
                float4 vv = ((const float4*)&ldsu[hw][u][0])[qq];
                h[u] = fmaf(vv.x, w2col[4 * qq + 0], h[u]);
                h[u] = fmaf(vv.y, w2col[4 * qq + 1], h[u]);
                h[u] = fmaf(vv.z, w2col[4 * qq + 2], h[u]);
                h[u] = fmaf(vv.w, w2col[4 * qq + 3], h[u]);
            }
        }
#pragma unroll
        for (int u = 0; u < NPH; u++) {
            float hv = fmaxf(h[u], 0.f);
            out[(size_t)(n0 + u) * 32 + c] = __float2half_rn(hv);
            sl += hv;
            sq += hv * hv;
        }
    } else {
        float w1col[32];
#pragma unroll
        for (int k = 0; k < 32; k++) w1col[k] = W1[k * 32 + c];
#pragma unroll
        for (int k = 0; k < 32; k++) asm volatile("" : "+v"(w1col[k]));
        const float b1c = B1[c];
        float tv[NPH];
#pragma unroll
        for (int u = 0; u < NPH; u++) tv[u] = b1c;
#pragma unroll
        for (int qq = 0; qq < 8; qq++) {
#pragma unroll
            for (int u = 0; u < NPH; u++) {
                float4 uu = ((const float4*)&ldsu[hw][u][0])[qq];
                tv[u] = fmaf(uu.x, w1col[4 * qq + 0], tv[u]);
                tv[u] = fmaf(uu.y, w1col[4 * qq + 1], tv[u]);
                tv[u] = fmaf(uu.z, w1col[4 * qq + 2], tv[u]);
                tv[u] = fmaf(uu.w, w1col[4 * qq + 3], tv[u]);
            }
        }
#pragma unroll
        for (int u = 0; u < NPH; u++) ldsv[hw][u][c] = fmaxf(tv[u], 0.f);  // same-wave vis
        float h[NPH];
#pragma unroll
        for (int u = 0; u < NPH; u++) h[u] = b2c;
#pragma unroll
        for (int qq = 0; qq < 8; qq++) {
#pragma unroll
            for (int u = 0; u < NPH; u++) {
                float4 vv = ((const float4*)&ldsv[hw][u][0])[qq];
                h[u] = fmaf(vv.x, w2col[4 * qq + 0], h[u]);
                h[u] = fmaf(vv.y, w2col[4 * qq + 1], h[u]);
                h[u] = fmaf(vv.z, w2col[4 * qq + 2], h[u]);
                h[u] = fmaf(vv.w, w2col[4 * qq + 3], h[u]);
            }
        }
#pragma unroll
        for (int u = 0; u < NPH; u++) {
            float hv = fmaxf(h[u], 0.f);
            if (MODE == 2) {
                atomicAdd(&pooledraw[batch[n0 + u] * HID + c], hv);
            } else {
                out[(size_t)(n0 + u) * 32 + c] = __float2half_rn(hv);
            }
            sl += hv;
            sq += hv * hv;
        }
    }

    atomicAdd(&ssum[c], sl);
    atomicAdd(&ssum[32 + c], sq);
    __syncthreads();
    if (t < 64) atomicAdd(&sums[(blockIdx.x & (NCOPY - 1)) * 64 + t], ssum[t]);
}

// ---------------- BN finalize: fold NCOPY copies -> scsh ----------------

__global__ void bnfin_kernel(const float* __restrict__ sums, const float* __restrict__ g,
                             const float* __restrict__ bt, float* __restrict__ scsh) {
    __shared__ float red[64];
    int t = threadIdx.x;
    if (t < 64) {
        float acc = 0.f;
#pragma unroll 8
        for (int k = 0; k < NCOPY; k++) acc += sums[k * 64 + t];
        red[t] = acc;
    }
    __syncthreads();
    if (t < HID) {
        float m = red[t] * (1.0f / N_NODES);
        float var = red[HID + t] * (1.0f / N_NODES) - m * m;
        var = fmaxf(var, 0.f);
        float sc = g[t] * rsqrtf(var + BN_EPS);
        scsh[t] = sc;
        scsh[HID + t] = bt[t] - m * sc;
    }
}

// ---------------- FC (applies layer-4 BN affine to raw pooled sums) ----------------

__global__ void fc_kernel(const float* __restrict__ praw, const int* __restrict__ cnt,
                          const float* __restrict__ scsh4, const float* __restrict__ fcw,
                          const float* __restrict__ fcb, float* __restrict__ out) {
    __shared__ float w[HID * OUTD];
    __shared__ float aff[2 * HID];
    for (int i = threadIdx.x; i < HID * OUTD; i += 256) w[i] = fcw[i];
    if (threadIdx.x < 2 * HID) aff[threadIdx.x] = scsh4[threadIdx.x];
    __syncthreads();
    int idx = blockIdx.x * 256 + threadIdx.x;
    if (idx >= N_GRAPHS * OUTD) return;
    int g = idx >> 7;
    int o = idx & 127;
    float cg = (float)cnt[g];
    float acc = fcb[o];
#pragma unroll
    for (int k = 0; k < HID; k++) {
        float paff = fmaf(praw[g * HID + k], aff[k], cg * aff[HID + k]);
        acc = fmaf(paff, w[k * OUTD + o], acc);
    }
    out[idx] = fmaxf(acc, 0.f);
}

// ---------------- Launch ----------------

extern "C" void kernel_launch(void* const* d_in, const int* in_sizes, int n_in,
                              void* d_out, int out_size, void* d_ws, size_t ws_size,
                              hipStream_t stream) {
    const float* x = (const float*)d_in[0];
    const int* ei = (const int*)d_in[1];
    const int* batch = (const int*)d_in[2];
    const float* w1_0 = (const float*)d_in[3];
    const float* b1_0 = (const float*)d_in[4];
    const float* w2_0 = (const float*)d_in[5];
    const float* b2_0 = (const float*)d_in[6];
    const float* w1 = (const float*)d_in[7];
    const float* b1 = (const float*)d_in[8];
    const float* w2 = (const float*)d_in[9];
    const float* b2 = (const float*)d_in[10];
    const float* gamma = (const float*)d_in[11];
    const float* beta = (const float*)d_in[12];
    const float* fc_w = (const float*)d_in[13];
    const float* fc_b = (const float*)d_in[14];
    float* out = (float*)d_out;

    const int* e_src = ei;
    const int* e_dst = ei + N_EDGES;

    char* ws = (char*)d_ws;
    size_t off = 0;
    auto alloc = [&](size_t n) {
        void* p = ws + off;
        off += (n + 255) & ~(size_t)255;
        return p;
    };
    int* row_start = (int*)alloc((size_t)(N_NODES + 1) * 4);
    int* csr = (int*)alloc((size_t)N_EDGES * 4);
    int* bbase = (int*)alloc((size_t)NBUCK * 4);
    int* staging = (int*)alloc((size_t)NBUCK * BCAP2 * 4);
    unsigned int* hA = (unsigned int*)alloc((size_t)N_NODES * 16 * 4);  // fp16x2 packed
    unsigned int* hB = (unsigned int*)alloc((size_t)N_NODES * 16 * 4);  // fp16x2 packed
    float* degf = (float*)alloc((size_t)N_NODES * 4);
    float* scsh = (float*)alloc(5 * 2 * HID * 4);
    int* cnt = (int*)alloc((size_t)N_GRAPHS * 4);
    // zero-initialized region (single memset): gcur | bnsums | pooled
    size_t zero_base = off;
    int* gcur = (int*)alloc((size_t)NBUCK * 4);
    float* bnsums = (float*)alloc((size_t)5 * NCOPY * 64 * 4);
    float* pooled = (float*)alloc((size_t)N_GRAPHS * HID * 4);
    size_t zero_len = off - zero_base;

    hipMemsetAsync(ws + zero_base, 0, zero_len, stream);

    // CSR build: LDS-staged partition then per-bucket counting sort
    part1_kernel<<<P1_BLOCKS, 256, 0, stream>>>(e_src, e_dst, gcur, staging);
    csrbase_kernel<<<1, 256, 0, stream>>>(gcur, bbase, row_start);
    part2_kernel<<<NBUCK, 256, 0, stream>>>(gcur, bbase, staging, row_start, csr, degf);
    gcnt_kernel<<<(N_GRAPHS + 255) / 256, 256, 0, stream>>>(batch, cnt);

    const int nodeBlocks = (N_NODES + 255) / 256;

    // Layer 0: proj78 -> hA; gma<0> reads hA, writes hB
    proj78_kernel<<<nodeBlocks, 256, 0, stream>>>(x, w1_0, hA);
    gma_kernel<0><<<CPL_BLOCKS, 256, 0, stream>>>(
        hA, row_start, csr, nullptr, nullptr, b1_0, nullptr, w2_0, b2_0, (__half*)hB, bnsums,
        nullptr, nullptr);
    bnfin_kernel<<<1, 64, 0, stream>>>(bnsums, gamma, beta, scsh);

    // Layers 1..4: alternate buffers (read cur, write nxt) — no in-kernel race
    unsigned int* cur = hB;
    unsigned int* nxt = hA;
    for (int l = 1; l < 5; l++) {
        int i = l - 1;
        if (l < 4) {
            gma_kernel<1><<<CPL_BLOCKS, 256, 0, stream>>>(
                cur, row_start, csr, degf, scsh + (l - 1) * 2 * HID, b1 + (size_t)i * HID,
                w1 + (size_t)i * HID * HID, w2 + (size_t)i * HID * HID, b2 + (size_t)i * HID,
                (__half*)nxt, bnsums + (size_t)l * NCOPY * 64, nullptr, nullptr);
            unsigned int* tmp = cur; cur = nxt; nxt = tmp;
        } else {
            gma_kernel<2><<<CPL_BLOCKS, 256, 0, stream>>>(
                cur, row_start, csr, degf, scsh + (l - 1) * 2 * HID, b1 + (size_t)i * HID,
                w1 + (size_t)i * HID * HID, w2 + (size_t)i * HID * HID, b2 + (size_t)i * HID,
                nullptr, bnsums + (size_t)l * NCOPY * 64, batch, pooled);
        }
        bnfin_kernel<<<1, 64, 0, stream>>>(bnsums + (size_t)l * NCOPY * 64, gamma + l * HID,
                                           beta + l * HID, scsh + l * 2 * HID);
    }

    // FC (applies layer-4 affine to raw pooled sums)
    fc_kernel<<<(N_GRAPHS * OUTD + 255) / 256, 256, 0, stream>>>(
        pooled, cnt, scsh + 4 * 2 * HID, fc_w, fc_b, out);
}

// Round 18
// 410.931 us; speedup vs baseline: 1.1071x; 1.1071x over previous
//
#include <hip/hip_runtime.h>
#include <hip/hip_fp16.h>

#define N_NODES 100000
#define N_EDGES 3200000
#define N_GRAPHS 2048
#define MOL 78
#define HID 32
#define OUTD 128
#define BN_EPS 1e-5f

// Partition: buckets of 256 nodes (dst >> 8)
#define NBUCK ((N_NODES + 255) / 256)  // 391
#define BCAP2 9216                     // mean 8184, sigma ~90 -> +11 sigma
#define EPB 4096                       // edges per part1 block
#define P1_BLOCKS ((N_EDGES + EPB - 1) / EPB)  // 782

#define NPH 4                             // nodes per half-wave
#define CPL_BLOCKS (N_NODES / (8 * NPH))  // 3125 (exact)

#define NCOPY 64  // BN-sum accumulator copies (kills same-address atomic serialization)

// fp16 payload helpers (RNE pack, exact unpack)
__device__ inline unsigned int pkh2(float a, float b) {
    __half2 h = __halves2half2(__float2half_rn(a), __float2half_rn(b));
    return *(unsigned int*)&h;
}
__device__ inline float hlo(unsigned int v) {
    __half2 h = *(__half2*)&v;
    return __low2float(h);
}
__device__ inline float hhi(unsigned int v) {
    __half2 h = *(__half2*)&v;
    return __high2float(h);
}

// ---------------- CSR build: LDS-staged two-pass bucket sort ----------------

__global__ __launch_bounds__(256) void part1_kernel(const int* __restrict__ src,
                                                    const int* __restrict__ dst,
                                                    int* __restrict__ gcur,
                                                    int* __restrict__ staging) {
    __shared__ int hist[NBUCK];
    __shared__ int lofs[NBUCK];
    __shared__ int lcur[NBUCK];
    __shared__ int gb[NBUCK];
    __shared__ int pk[EPB];
    __shared__ unsigned short bkt[EPB];
    __shared__ int sc[256];
    const int t = threadIdx.x;
    const int base = blockIdx.x * EPB;
    const int nedge = min(EPB, N_EDGES - base);

    for (int i = t; i < NBUCK; i += 256) hist[i] = 0;
    __syncthreads();
    for (int i = t; i < nedge; i += 256) atomicAdd(&hist[dst[base + i] >> 8], 1);
    __syncthreads();

    int a0 = (2 * t < NBUCK) ? hist[2 * t] : 0;
    int a1 = (2 * t + 1 < NBUCK) ? hist[2 * t + 1] : 0;
    int tot = a0 + a1;
    sc[t] = tot;
    __syncthreads();
    for (int off = 1; off < 256; off <<= 1) {
        int add = (t >= off) ? sc[t - off] : 0;
        __syncthreads();
        sc[t] += add;
        __syncthreads();
    }
    int excl = sc[t] - tot;
    if (2 * t < NBUCK) { lofs[2 * t] = excl; lcur[2 * t] = excl; }
    if (2 * t + 1 < NBUCK) { lofs[2 * t + 1] = excl + a0; lcur[2 * t + 1] = excl + a0; }
    __syncthreads();

    for (int i = t; i < nedge; i += 256) {
        int d = dst[base + i];
        int s = src[base + i];
        int b = d >> 8;
        int p = atomicAdd(&lcur[b], 1);
        pk[p] = (s << 8) | (d & 255);
        bkt[p] = (unsigned short)b;
    }
    __syncthreads();

    for (int b = t; b < NBUCK; b += 256) {
        int c = lcur[b] - lofs[b];
        gb[b] = c ? atomicAdd(&gcur[b], c) : 0;
    }
    __syncthreads();

    for (int i = t; i < nedge; i += 256) {
        int b = bkt[i];
        staging[(size_t)b * BCAP2 + gb[b] + (i - lofs[b])] = pk[i];
    }
}

__global__ void csrbase_kernel(const int* __restrict__ gcur, int* __restrict__ bbase,
                               int* __restrict__ row_start) {
    int t = threadIdx.x;
    int a0 = (2 * t < NBUCK) ? gcur[2 * t] : 0;
    int a1 = (2 * t + 1 < NBUCK) ? gcur[2 * t + 1] : 0;
    int tot = a0 + a1;
    __shared__ int sc[256];
    sc[t] = tot;
    __syncthreads();
    for (int off = 1; off < 256; off <<= 1) {
        int add = (t >= off) ? sc[t - off] : 0;
        __syncthreads();
        sc[t] += add;
        __syncthreads();
    }
    int excl = sc[t] - tot;
    if (2 * t < NBUCK) bbase[2 * t] = excl;
    if (2 * t + 1 < NBUCK) bbase[2 * t + 1] = excl + a0;
    if (t == 0) row_start[N_NODES] = N_EDGES;
}

__global__ __launch_bounds__(256) void part2_kernel(const int* __restrict__ gcur,
                                                    const int* __restrict__ bbase,
                                                    const int* __restrict__ staging,
                                                    int* __restrict__ row_start,
                                                    int* __restrict__ csr,
                                                    float* __restrict__ degf) {
    int b = blockIdx.x, t = threadIdx.x;
    __shared__ int ldeg[256];
    __shared__ int lex[256];
    __shared__ int sc[256];
    ldeg[t] = 0;
    __syncthreads();
    int cnt = gcur[b];
    int base = bbase[b];
    const int* sp = staging + (size_t)b * BCAP2;
    for (int i = t; i < cnt; i += 256) atomicAdd(&ldeg[sp[i] & 255], 1);
    __syncthreads();
    int v = ldeg[t];
    sc[t] = v;
    __syncthreads();
    for (int off = 1; off < 256; off <<= 1) {
        int add = (t >= off) ? sc[t - off] : 0;
        __syncthreads();
        sc[t] += add;
        __syncthreads();
    }
    int excl = sc[t] - v;
    int node = b * 256 + t;
    if (node < N_NODES) {
        row_start[node] = base + excl;
        degf[node] = 1.0f + (float)v;
    }
    lex[t] = base + excl;
    __syncthreads();
    for (int i = t; i < cnt; i += 256) {
        int pk = sp[i];
        int p = atomicAdd(&lex[pk & 255], 1);
        csr[p] = pk >> 8;
    }
}

// ---------------- Graph node counts (batch is sorted) ----------------

__global__ void gcnt_kernel(const int* __restrict__ batch, int* __restrict__ cnt) {
    int g = blockIdx.x * blockDim.x + threadIdx.x;
    if (g >= N_GRAPHS) return;
    auto lb = [&](int key) {
        int lo = 0, hi = N_NODES;
        while (lo < hi) {
            int mid = (lo + hi) >> 1;
            if (batch[mid] < key) lo = mid + 1; else hi = mid;
        }
        return lo;
    };
    cnt[g] = lb(g + 1) - lb(g);
}

// ---------------- Layer-0 projection (78 -> 32), fp16 output ----------------

__global__ __launch_bounds__(256) void proj78_kernel(const float* __restrict__ in,
                                                     const float* __restrict__ W1,
                                                     unsigned int* __restrict__ y) {
    __shared__ float w1s[MOL * HID];
    for (int i = threadIdx.x; i < MOL * HID; i += 256) w1s[i] = W1[i];
    __syncthreads();
    const int node = blockIdx.x * 256 + threadIdx.x;
    if (node >= N_NODES) return;
    const float* row = in + (size_t)node * MOL;
    float acc[HID];
#pragma unroll
    for (int j = 0; j < HID; j++) acc[j] = 0.f;
    const float4* w1v = (const float4*)w1s;
    for (int k = 0; k < MOL; k++) {
        float xv = row[k];
#pragma unroll
        for (int q = 0; q < 8; q++) {
            float4 wv = w1v[k * 8 + q];
            acc[4 * q + 0] = fmaf(xv, wv.x, acc[4 * q + 0]);
            acc[4 * q + 1] = fmaf(xv, wv.y, acc[4 * q + 1]);
            acc[4 * q + 2] = fmaf(xv, wv.z, acc[4 * q + 2]);
            acc[4 * q + 3] = fmaf(xv, wv.w, acc[4 * q + 3]);
        }
    }
    uint4* o = (uint4*)(y + (size_t)node * 16);
#pragma unroll
    for (int g = 0; g < 4; g++) {
        uint4 u;
        u.x = pkh2(acc[8 * g + 0], acc[8 * g + 1]);
        u.y = pkh2(acc[8 * g + 2], acc[8 * g + 3]);
        u.z = pkh2(acc[8 * g + 4], acc[8 * g + 5]);
        u.w = pkh2(acc[8 * g + 6], acc[8 * g + 7]);
        o[g] = u;
    }
}

// ---------------- Fused gather + MLP + BN stats (one kernel per layer) ----------------
// MODE 0: layer 0 — v = ReLU(agg + B1) at LDS write; W2 matvec.
// MODE 1: mid layers — u = sc*agg + degf*sh at LDS write; W1 + ReLU; W2.
// MODE 2: last layer — like MODE 1 but pools raw h via atomics.
// Weights live in PADDED-TRANSPOSED LDS ([32][33]): lane c reads column c at bank
// (c+k)%32 — conflict-free. (Register-resident weight columns failed twice: LLVM
// rematerializes the 64 global loads inside the fmaf loops at any launch_bounds.)
// y (gather input) and out MUST be different buffers (round-14 race).

template <int MODE>
__global__ __launch_bounds__(256) void gma_kernel(
    const unsigned int* __restrict__ y, const int* __restrict__ rs, const int* __restrict__ csr,
    const float* __restrict__ degf, const float* __restrict__ scsh_prev,
    const float* __restrict__ B1, const float* __restrict__ W1, const float* __restrict__ W2,
    const float* __restrict__ B2, __half* __restrict__ out, float* __restrict__ sums,
    const int* __restrict__ batch, float* __restrict__ pooledraw) {
    __shared__ float ldsu[8][NPH][HID];
    __shared__ float ldsv[8][NPH][HID];
    __shared__ float w2T[HID][HID + 1];
    __shared__ float w1T[HID][HID + 1];
    __shared__ float ssum[64];
    const int t = threadIdx.x;
    const int hw = t >> 5;
    const int hl = t & 31;
    const int s = hl >> 2;  // slot 0..7
    const int q = hl & 3;   // quad: channels 8q..8q+7
    const int c = hl;       // channel for matvec phase

    // stage transposed weights (coalesced global reads; conflict-free LDS writes)
    for (int idx = t; idx < HID * HID; idx += 256) {
        int k = idx >> 5, cc = idx & 31;
        w2T[cc][k] = W2[idx];
        if (MODE != 0) w1T[cc][k] = W1[idx];
    }
    if (t < 64) ssum[t] = 0.f;
    __syncthreads();

    // per-quad transform params (used by slot-0 lanes at LDS write)
    float4 p0a, p0b, p1a, p1b;
    if (MODE == 0) {
        p0a = ((const float4*)B1)[2 * q];
        p0b = ((const float4*)B1)[2 * q + 1];
    } else {
        p0a = ((const float4*)scsh_prev)[2 * q];          // sc[8q..]
        p0b = ((const float4*)scsh_prev)[2 * q + 1];
        p1a = ((const float4*)(scsh_prev + HID))[2 * q];  // sh[8q..]
        p1b = ((const float4*)(scsh_prev + HID))[2 * q + 1];
    }

    const int n0 = (blockIdx.x * 8 + hw) * NPH;
    const uint4* rows = (const uint4*)y;

    // ---- Phase 1: gather NPH nodes ----
    for (int u = 0; u < NPH; u++) {
        const int n = n0 + u;
        float acc[8];
#pragma unroll
        for (int i = 0; i < 8; i++) acc[i] = 0.f;
        if (s == 0) {
            uint4 w = rows[(size_t)n * 4 + q];
            acc[0] = hlo(w.x); acc[1] = hhi(w.x);
            acc[2] = hlo(w.y); acc[3] = hhi(w.y);
            acc[4] = hlo(w.z); acc[5] = hhi(w.z);
            acc[6] = hlo(w.w); acc[7] = hhi(w.w);
        }
        int e0 = rs[n], e1 = rs[n + 1];
        int k = e0 + s;
        for (; k + 8 < e1; k += 16) {
            uint4 a = rows[(size_t)csr[k] * 4 + q];
            uint4 b = rows[(size_t)csr[k + 8] * 4 + q];
            acc[0] += hlo(a.x) + hlo(b.x);
            acc[1] += hhi(a.x) + hhi(b.x);
            acc[2] += hlo(a.y) + hlo(b.y);
            acc[3] += hhi(a.y) + hhi(b.y);
            acc[4] += hlo(a.z) + hlo(b.z);
            acc[5] += hhi(a.z) + hhi(b.z);
            acc[6] += hlo(a.w) + hlo(b.w);
            acc[7] += hhi(a.w) + hhi(b.w);
        }
        if (k < e1) {
            uint4 a = rows[(size_t)csr[k] * 4 + q];
            acc[0] += hlo(a.x); acc[1] += hhi(a.x);
            acc[2] += hlo(a.y); acc[3] += hhi(a.y);
            acc[4] += hlo(a.z); acc[5] += hhi(a.z);
            acc[6] += hlo(a.w); acc[7] += hhi(a.w);
        }
#pragma unroll
        for (int m = 4; m <= 16; m <<= 1) {
#pragma unroll
            for (int i = 0; i < 8; i++) acc[i] += __shfl_xor(acc[i], m, 32);
        }
        if (s == 0) {
            float o[8];
            if (MODE == 0) {
                o[0] = fmaxf(acc[0] + p0a.x, 0.f); o[1] = fmaxf(acc[1] + p0a.y, 0.f);
                o[2] = fmaxf(acc[2] + p0a.z, 0.f); o[3] = fmaxf(acc[3] + p0a.w, 0.f);
                o[4] = fmaxf(acc[4] + p0b.x, 0.f); o[5] = fmaxf(acc[5] + p0b.y, 0.f);
                o[6] = fmaxf(acc[6] + p0b.z, 0.f); o[7] = fmaxf(acc[7] + p0b.w, 0.f);
            } else {
                float dn = degf[n];
                o[0] = fmaf(acc[0], p0a.x, dn * p1a.x);
                o[1] = fmaf(acc[1], p0a.y, dn * p1a.y);
                o[2] = fmaf(acc[2], p0a.z, dn * p1a.z);
                o[3] = fmaf(acc[3], p0a.w, dn * p1a.w);
                o[4] = fmaf(acc[4], p0b.x, dn * p1b.x);
                o[5] = fmaf(acc[5], p0b.y, dn * p1b.y);
                o[6] = fmaf(acc[6], p0b.z, dn * p1b.z);
                o[7] = fmaf(acc[7], p0b.w, dn * p1b.w);
            }
            float4* d = (float4*)&ldsu[hw][u][q * 8];
            d[0] = make_float4(o[0], o[1], o[2], o[3]);
            d[1] = make_float4(o[4], o[5], o[6], o[7]);
        }
    }

    // ---- Phase 2: matvec(s) from LDS-transposed weights, ILP=NPH chains ----
    const float b2c = B2[c];
    float sl = 0.f, sq = 0.f;

    if (MODE == 0) {
        float h[NPH];
#pragma unroll
        for (int u = 0; u < NPH; u++) h[u] = b2c;
#pragma unroll
        for (int qq = 0; qq < 8; qq++) {
            float wa = w2T[c][4 * qq + 0], wb = w2T[c][4 * qq + 1];
            float wc2 = w2T[c][4 * qq + 2], wd = w2T[c][4 * qq + 3];
#pragma unroll
            for (int u = 0; u < NPH; u++) {
                float4 vv = ((const float4*)&ldsu[hw][u][0])[qq];
                h[u] = fmaf(vv.x, wa, h[u]);
                h[u] = fmaf(vv.y, wb, h[u]);
                h[u] = fmaf(vv.z, wc2, h[u]);
                h[u] = fmaf(vv.w, wd, h[u]);
            }
        }
#pragma unroll
        for (int u = 0; u < NPH; u++) {
            float hv = fmaxf(h[u], 0.f);
            out[(size_t)(n0 + u) * 32 + c] = __float2half_rn(hv);
            sl += hv;
            sq += hv * hv;
        }
    } else {
        const float b1c = B1[c];
        float tv[NPH];
#pragma unroll
        for (int u = 0; u < NPH; u++) tv[u] = b1c;
#pragma unroll
        for (int qq = 0; qq < 8; qq++) {
            float wa = w1T[c][4 * qq + 0], wb = w1T[c][4 * qq + 1];
            float wc1 = w1T[c][4 * qq + 2], wd = w1T[c][4 * qq + 3];
#pragma unroll
            for (int u = 0; u < NPH; u++) {
                float4 uu = ((const float4*)&ldsu[hw][u][0])[qq];
                tv[u] = fmaf(uu.x, wa, tv[u]);
                tv[u] = fmaf(uu.y, wb, tv[u]);
                tv[u] = fmaf(uu.z, wc1, tv[u]);
                tv[u] = fmaf(uu.w, wd, tv[u]);
            }
        }
#pragma unroll
        for (int u = 0; u < NPH; u++) ldsv[hw][u][c] = fmaxf(tv[u], 0.f);  // same-wave vis
        float h[NPH];
#pragma unroll
        for (int u = 0; u < NPH; u++) h[u] = b2c;
#pragma unroll
        for (int qq = 0; qq < 8; qq++) {
            float wa = w2T[c][4 * qq + 0], wb = w2T[c][4 * qq + 1];
            float wc2 = w2T[c][4 * qq + 2], wd = w2T[c][4 * qq + 3];
#pragma unroll
            for (int u = 0; u < NPH; u++) {
                float4 vv = ((const float4*)&ldsv[hw][u][0])[qq];
                h[u] = fmaf(vv.x, wa, h[u]);
                h[u] = fmaf(vv.y, wb, h[u]);
                h[u] = fmaf(vv.z, wc2, h[u]);
                h[u] = fmaf(vv.w, wd, h[u]);
            }
        }
#pragma unroll
        for (int u = 0; u < NPH; u++) {
            float hv = fmaxf(h[u], 0.f);
            if (MODE == 2) {
                atomicAdd(&pooledraw[batch[n0 + u] * HID + c], hv);
            } else {
                out[(size_t)(n0 + u) * 32 + c] = __float2half_rn(hv);
            }
            sl += hv;
            sq += hv * hv;
        }
    }

    atomicAdd(&ssum[c], sl);
    atomicAdd(&ssum[32 + c], sq);
    __syncthreads();
    if (t < 64) atomicAdd(&sums[(blockIdx.x & (NCOPY - 1)) * 64 + t], ssum[t]);
}

// ---------------- BN finalize: fold NCOPY copies -> scsh ----------------

__global__ void bnfin_kernel(const float* __restrict__ sums, const float* __restrict__ g,
                             const float* __restrict__ bt, float* __restrict__ scsh) {
    __shared__ float red[64];
    int t = threadIdx.x;
    if (t < 64) {
        float acc = 0.f;
#pragma unroll 8
        for (int k = 0; k < NCOPY; k++) acc += sums[k * 64 + t];
        red[t] = acc;
    }
    __syncthreads();
    if (t < HID) {
        float m = red[t] * (1.0f / N_NODES);
        float var = red[HID + t] * (1.0f / N_NODES) - m * m;
        var = fmaxf(var, 0.f);
        float sc = g[t] * rsqrtf(var + BN_EPS);
        scsh[t] = sc;
        scsh[HID + t] = bt[t] - m * sc;
    }
}

// ---------------- FC (applies layer-4 BN affine to raw pooled sums) ----------------

__global__ void fc_kernel(const float* __restrict__ praw, const int* __restrict__ cnt,
                          const float* __restrict__ scsh4, const float* __restrict__ fcw,
                          const float* __restrict__ fcb, float* __restrict__ out) {
    __shared__ float w[HID * OUTD];
    __shared__ float aff[2 * HID];
    for (int i = threadIdx.x; i < HID * OUTD; i += 256) w[i] = fcw[i];
    if (threadIdx.x < 2 * HID) aff[threadIdx.x] = scsh4[threadIdx.x];
    __syncthreads();
    int idx = blockIdx.x * 256 + threadIdx.x;
    if (idx >= N_GRAPHS * OUTD) return;
    int g = idx >> 7;
    int o = idx & 127;
    float cg = (float)cnt[g];
    float acc = fcb[o];
#pragma unroll
    for (int k = 0; k < HID; k++) {
        float paff = fmaf(praw[g * HID + k], aff[k], cg * aff[HID + k]);
        acc = fmaf(paff, w[k * OUTD + o], acc);
    }
    out[idx] = fmaxf(acc, 0.f);
}

// ---------------- Launch ----------------

extern "C" void kernel_launch(void* const* d_in, const int* in_sizes, int n_in,
                              void* d_out, int out_size, void* d_ws, size_t ws_size,
                              hipStream_t stream) {
    const float* x = (const float*)d_in[0];
    const int* ei = (const int*)d_in[1];
    const int* batch = (const int*)d_in[2];
    const float* w1_0 = (const float*)d_in[3];
    const float* b1_0 = (const float*)d_in[4];
    const float* w2_0 = (const float*)d_in[5];
    const float* b2_0 = (const float*)d_in[6];
    const float* w1 = (const float*)d_in[7];
    const float* b1 = (const float*)d_in[8];
    const float* w2 = (const float*)d_in[9];
    const float* b2 = (const float*)d_in[10];
    const float* gamma = (const float*)d_in[11];
    const float* beta = (const float*)d_in[12];
    const float* fc_w = (const float*)d_in[13];
    const float* fc_b = (const float*)d_in[14];
    float* out = (float*)d_out;

    const int* e_src = ei;
    const int* e_dst = ei + N_EDGES;

    char* ws = (char*)d_ws;
    size_t off = 0;
    auto alloc = [&](size_t n) {
        void* p = ws + off;
        off += (n + 255) & ~(size_t)255;
        return p;
    };
    int* row_start = (int*)alloc((size_t)(N_NODES + 1) * 4);
    int* csr = (int*)alloc((size_t)N_EDGES * 4);
    int* bbase = (int*)alloc((size_t)NBUCK * 4);
    int* staging = (int*)alloc((size_t)NBUCK * BCAP2 * 4);
    unsigned int* hA = (unsigned int*)alloc((size_t)N_NODES * 16 * 4);  // fp16x2 packed
    unsigned int* hB = (unsigned int*)alloc((size_t)N_NODES * 16 * 4);  // fp16x2 packed
    float* degf = (float*)alloc((size_t)N_NODES * 4);
    float* scsh = (float*)alloc(5 * 2 * HID * 4);
    int* cnt = (int*)alloc((size_t)N_GRAPHS * 4);
    // zero-initialized region (single memset): gcur | bnsums | pooled
    size_t zero_base = off;
    int* gcur = (int*)alloc((size_t)NBUCK * 4);
    float* bnsums = (float*)alloc((size_t)5 * NCOPY * 64 * 4);
    float* pooled = (float*)alloc((size_t)N_GRAPHS * HID * 4);
    size_t zero_len = off - zero_base;

    hipMemsetAsync(ws + zero_base, 0, zero_len, stream);

    // CSR build: LDS-staged partition then per-bucket counting sort
    part1_kernel<<<P1_BLOCKS, 256, 0, stream>>>(e_src, e_dst, gcur, staging);
    csrbase_kernel<<<1, 256, 0, stream>>>(gcur, bbase, row_start);
    part2_kernel<<<NBUCK, 256, 0, stream>>>(gcur, bbase, staging, row_start, csr, degf);
    gcnt_kernel<<<(N_GRAPHS + 255) / 256, 256, 0, stream>>>(batch, cnt);

    const int nodeBlocks = (N_NODES + 255) / 256;

    // Layer 0: proj78 -> hA; gma<0> reads hA, writes hB
    proj78_kernel<<<nodeBlocks, 256, 0, stream>>>(x, w1_0, hA);
    gma_kernel<0><<<CPL_BLOCKS, 256, 0, stream>>>(
        hA, row_start, csr, nullptr, nullptr, b1_0, nullptr, w2_0, b2_0, (__half*)hB, bnsums,
        nullptr, nullptr);
    bnfin_kernel<<<1, 64, 0, stream>>>(bnsums, gamma, beta, scsh);

    // Layers 1..4: alternate buffers (read cur, write nxt) — no in-kernel race
    unsigned int* cur = hB;
    unsigned int* nxt = hA;
    for (int l = 1; l < 5; l++) {
        int i = l - 1;
        if (l < 4) {
            gma_kernel<1><<<CPL_BLOCKS, 256, 0, stream>>>(
                cur, row_start, csr, degf, scsh + (l - 1) * 2 * HID, b1 + (size_t)i * HID,
                w1 + (size_t)i * HID * HID, w2 + (size_t)i * HID * HID, b2 + (size_t)i * HID,
                (__half*)nxt, bnsums + (size_t)l * NCOPY * 64, nullptr, nullptr);
            unsigned int* tmp = cur; cur = nxt; nxt = tmp;
        } else {
            gma_kernel<2><<<CPL_BLOCKS, 256, 0, stream>>>(
                cur, row_start, csr, degf, scsh + (l - 1) * 2 * HID, b1 + (size_t)i * HID,
                w1 + (size_t)i * HID * HID, w2 + (size_t)i * HID * HID, b2 + (size_t)i * HID,
                nullptr, bnsums + (size_t)l * NCOPY * 64, batch, pooled);
        }
        bnfin_kernel<<<1, 64, 0, stream>>>(bnsums + (size_t)l * NCOPY * 64, gamma + l * HID,
                                           beta + l * HID, scsh + l * 2 * HID);
    }

    // FC (applies layer-4 affine to raw pooled sums)
    fc_kernel<<<(N_GRAPHS * OUTD + 255) / 256, 256, 0, stream>>>(
        pooled, cnt, scsh + 4 * 2 * HID, fc_w, fc_b, out);
}